// Round 10
// baseline (317.139 us; speedup 1.0000x reference)
//
#include <hip/hip_runtime.h>

#define B_ 32
#define T_ 24
#define N_ 2048
#define D_ 64
#define K_ 32
#define H_ 16
#define NB 8

typedef __attribute__((ext_vector_type(8))) short bf16x8;
typedef __attribute__((ext_vector_type(4))) float f32x4;
typedef __attribute__((ext_vector_type(4))) int i32x4;

__device__ __forceinline__ unsigned short f2bf(float f) {
    unsigned int u = __float_as_uint(f);
    return (unsigned short)((u + 0x7FFFu + ((u >> 16) & 1u)) >> 16);
}
__device__ __forceinline__ float bf2f(unsigned short h) {
    return __uint_as_float(((unsigned int)h) << 16);
}

// M2 (bf16), block-sliced for NB=8: flat = (n>>3)*4608 + t*192 + (n&7)*24 + t2
__global__ void k_prepM(const float* __restrict__ ne, const float* __restrict__ adj,
                        unsigned short* __restrict__ M2) {
    __shared__ float s_ne[K_];
    __shared__ float s_ad[H_ * T_];
    const int n = blockIdx.x;
    const int tid = threadIdx.x;  // 64 threads
    if (tid < K_) s_ne[tid] = ne[n * K_ + tid];
    __syncthreads();
    for (int f = tid; f < H_ * T_; f += 64) {
        const int h = f / T_, t = f % T_;
        float a = 0.f;
#pragma unroll
        for (int k = 0; k < K_; ++k) a += s_ne[k] * adj[(k * H_ + h) * T_ + t];
        s_ad[f] = a;
    }
    __syncthreads();
    unsigned short* dst = M2 + (size_t)(n >> 3) * (T_ * T_ * NB) + (n & 7) * T_;
    for (int m = tid; m < T_ * T_; m += 64) {
        const int t = m / T_, t2 = m % T_;
        float a = 0.f;
#pragma unroll
        for (int h = 0; h < H_; ++h) a += s_ad[h * T_ + t] * s_ad[h * T_ + t2];
        dst[t * (NB * T_) + t2] = f2bf(a);
    }
}

// Wt[bt][o][i] (bf16) = sum_k te[bt][k]*wp[k][i][o];  bias[bt][o] f32
__global__ __launch_bounds__(256) void k_prepW(const float* __restrict__ te,
                                               const float* __restrict__ wp,
                                               const float* __restrict__ bp,
                                               unsigned short* __restrict__ Wt,
                                               float* __restrict__ bias) {
    const int bt = blockIdx.x;   // 0..B*T-1
    const int tid = threadIdx.x; // 256
    __shared__ float s_te[K_];
    __shared__ float s_W[D_ * D_];  // [i][o] f32
    if (tid < K_) s_te[tid] = te[bt * K_ + tid];
    __syncthreads();
    float4 acc[4] = {};
    for (int k = 0; k < K_; ++k) {
        const float tk = s_te[k];
        const float4* row = (const float4*)(wp + (size_t)k * (D_ * D_));
#pragma unroll
        for (int i = 0; i < 4; ++i) {
            float4 v = row[tid + i * 256];
            acc[i].x += tk * v.x; acc[i].y += tk * v.y;
            acc[i].z += tk * v.z; acc[i].w += tk * v.w;
        }
    }
    float4* sW4 = (float4*)s_W;
#pragma unroll
    for (int i = 0; i < 4; ++i) sW4[tid + i * 256] = acc[i];
    if (tid < D_) {
        float a = 0.f;
#pragma unroll
        for (int k = 0; k < K_; ++k) a += s_te[k] * bp[k * D_ + tid];
        bias[bt * D_ + tid] = a;
    }
    __syncthreads();
    // transpose -> bf16: Wt[o][i]
    const int o = tid >> 2;
    const int i0 = (tid & 3) * 16;
    unsigned short* dst = Wt + (size_t)bt * (D_ * D_) + o * D_ + i0;
#pragma unroll
    for (int j = 0; j < 16; j += 4) {
        ushort4 u;
        u.x = f2bf(s_W[(i0 + j + 0) * D_ + o]);
        u.y = f2bf(s_W[(i0 + j + 1) * D_ + o]);
        u.z = f2bf(s_W[(i0 + j + 2) * D_ + o]);
        u.w = f2bf(s_W[(i0 + j + 3) * D_ + o]);
        *(ushort4*)(dst + j) = u;
    }
}

// Fused, NB=8, 256 threads (4 waves), 4 blocks/CU.
// Lane = (dh = lane>>3, n = lane&7); mix acc[3][8] = ret[t][n][dh*8+q].
// A-frags for MFMA built via ds_bpermute (no LDS round-trip, no extra barrier).
// s_eb slot layout: slot(dh,n) = dh*8 + (n^dh)  (conflict-free reads AND writes).
__global__ __launch_bounds__(256, 4) void k_fused(const float* __restrict__ eb,
                                                  const unsigned short* __restrict__ M2,
                                                  const unsigned short* __restrict__ Wt,
                                                  const float* __restrict__ bias,
                                                  float* __restrict__ out) {
    const int b = blockIdx.y;
    const int nb = blockIdx.x * NB;
    const int tid = threadIdx.x;
    const int wave = tid >> 6, lane = tid & 63;
    const int lr = lane & 15, lh = lane >> 4;
    const int ln = lane & 7;   // node within tile
    const int dh = lane >> 3;  // d-oct 0..7

    __shared__ unsigned short s_eb[T_ * NB * D_];  // 24576 B: [tp][64 slots][8 bf16]
    __shared__ unsigned short s_M[T_ * NB * T_];   //  9216 B: [t][n][tp]

    // ---- stage eb[b][:][nb:nb+8][:] -> LDS bf16 (12 float4/thread, coalesced) ----
    {
#pragma unroll
        for (int it = 0; it < 12; ++it) {
            const int f4 = it * 256 + tid;        // 0..3071
            const int t = f4 >> 7;
            const int rem = f4 & 127;
            const int n = rem >> 4;
            const int d0 = (rem & 15) * 4;
            const float4 v = *(const float4*)(eb + ((size_t)(b * T_ + t) * N_ + nb + n) * D_ + d0);
            ushort4 u;
            u.x = f2bf(v.x); u.y = f2bf(v.y); u.z = f2bf(v.z); u.w = f2bf(v.w);
            const int dh0 = d0 >> 3;
            const int slot = dh0 * 8 + (n ^ dh0);
            *(ushort4*)((char*)s_eb + t * 1024 + slot * 16 + (d0 & 7) * 2) = u;
        }
    }
    // ---- stage M block slice (linear uint copy) ----
    {
        const unsigned int* Mg = (const unsigned int*)(M2 + (size_t)blockIdx.x * (T_ * T_ * NB));
        unsigned int* Ml = (unsigned int*)s_M;
#pragma unroll
        for (int i = 0; i < 9; ++i) Ml[i * 256 + tid] = Mg[i * 256 + tid];
    }
    __syncthreads();

    const char* ebase = (const char*)s_eb + (dh * 8 + (ln ^ dh)) * 16;
    const unsigned short* mrow = s_M + ln * T_;  // + t*192 + tp
    const int addr0 = (lh * 8 + ln) * 4;          // bpermute byte addr (ret half 0)
    const int addr1 = ((lh + 4) * 8 + ln) * 4;    // ret half 1 (d 32..63)

    for (int pass = 0; pass < 2; ++pass) {
        const int tb = pass * 12 + wave * 3;

        float acc[3][8];
#pragma unroll
        for (int tt = 0; tt < 3; ++tt)
#pragma unroll
            for (int q = 0; q < 8; ++q) acc[tt][q] = 0.f;

#pragma unroll 4
        for (int tp = 0; tp < T_; ++tp) {
            const float m0 = bf2f(mrow[(tb + 0) * 192 + tp]);
            const float m1 = bf2f(mrow[(tb + 1) * 192 + tp]);
            const float m2 = bf2f(mrow[(tb + 2) * 192 + tp]);
            const bf16x8 e = *(const bf16x8*)(ebase + tp * 1024);
#pragma unroll
            for (int q = 0; q < 8; ++q) {
                const float ef = bf2f((unsigned short)e[q]);
                acc[0][q] += m0 * ef;
                acc[1][q] += m1 * ef;
                acc[2][q] += m2 * ef;
            }
        }

#pragma unroll
        for (int tt = 0; tt < 3; ++tt) {
            const int t = tb + tt;
            const int bt = b * T_ + t;

            // pack this lane's 8 ret values (bf16) into 4 dwords
            const int w0 = (int)((unsigned)f2bf(acc[tt][0]) | ((unsigned)f2bf(acc[tt][1]) << 16));
            const int w1 = (int)((unsigned)f2bf(acc[tt][2]) | ((unsigned)f2bf(acc[tt][3]) << 16));
            const int w2 = (int)((unsigned)f2bf(acc[tt][4]) | ((unsigned)f2bf(acc[tt][5]) << 16));
            const int w3 = (int)((unsigned)f2bf(acc[tt][6]) | ((unsigned)f2bf(acc[tt][7]) << 16));

            // redistribute to MFMA A-fragments: lane(lr,lh) needs ret[t][lr][lh*8+j]
            i32x4 a0v, a1v;
            a0v.x = __builtin_amdgcn_ds_bpermute(addr0, w0);
            a0v.y = __builtin_amdgcn_ds_bpermute(addr0, w1);
            a0v.z = __builtin_amdgcn_ds_bpermute(addr0, w2);
            a0v.w = __builtin_amdgcn_ds_bpermute(addr0, w3);
            a1v.x = __builtin_amdgcn_ds_bpermute(addr1, w0);
            a1v.y = __builtin_amdgcn_ds_bpermute(addr1, w1);
            a1v.z = __builtin_amdgcn_ds_bpermute(addr1, w2);
            a1v.w = __builtin_amdgcn_ds_bpermute(addr1, w3);
            const bf16x8 Af0 = __builtin_bit_cast(bf16x8, a0v);
            const bf16x8 Af1 = __builtin_bit_cast(bf16x8, a1v);

            const unsigned short* Wb = Wt + (size_t)bt * (D_ * D_);
            f32x4 C[4];
#pragma unroll
            for (int ot = 0; ot < 4; ++ot) {
                const int o = ot * 16 + lr;
                const float bv = bias[bt * D_ + o];
                const int dho = o >> 3;
#pragma unroll
                for (int r = 0; r < 4; ++r) {
                    const int nn = (lh & 1) * 4 + r;  // safe n (valid for lh<2)
                    const unsigned short ev = *(const unsigned short*)(
                        (const char*)s_eb + t * 1024 + (dho * 8 + (nn ^ dho)) * 16 + (o & 7) * 2);
                    C[ot][r] = bv + bf2f(ev);
                }
            }
#pragma unroll
            for (int ot = 0; ot < 4; ++ot) {
                const bf16x8 B0 = *(const bf16x8*)(Wb + (ot * 16 + lr) * D_ + lh * 8);
                const bf16x8 B1 = *(const bf16x8*)(Wb + (ot * 16 + lr) * D_ + 32 + lh * 8);
                C[ot] = __builtin_amdgcn_mfma_f32_16x16x32_bf16(Af0, B0, C[ot], 0, 0, 0);
                C[ot] = __builtin_amdgcn_mfma_f32_16x16x32_bf16(Af1, B1, C[ot], 0, 0, 0);
            }

            if (lh < 2) {
                float* obt = out + ((size_t)bt * N_ + nb) * D_;
#pragma unroll
                for (int ot = 0; ot < 4; ++ot) {
                    const int o = ot * 16 + lr;
#pragma unroll
                    for (int r = 0; r < 4; ++r) {
                        const int nn = lh * 4 + r;
                        float v = C[ot][r];
                        v = v >= 0.f ? v : 0.01f * v;
                        obt[(size_t)nn * D_ + o] = v;
                    }
                }
            }
        }
    }
}

extern "C" void kernel_launch(void* const* d_in, const int* in_sizes, int n_in,
                              void* d_out, int out_size, void* d_ws, size_t ws_size,
                              hipStream_t stream) {
    const float* eb  = (const float*)d_in[0];
    const float* ne  = (const float*)d_in[1];
    const float* te  = (const float*)d_in[2];
    const float* adj = (const float*)d_in[3];
    const float* wp  = (const float*)d_in[4];
    const float* bp  = (const float*)d_in[5];
    float* out = (float*)d_out;

    char* ws = (char*)d_ws;
    const size_t M_bytes  = (size_t)N_ * T_ * T_ * 2;       // 2,359,296 (bf16)
    const size_t Wt_bytes = (size_t)B_ * T_ * D_ * D_ * 2;  // 6,291,456
    unsigned short* M2 = (unsigned short*)ws;
    unsigned short* Wt = (unsigned short*)(ws + M_bytes);
    float* bias        = (float*)(ws + M_bytes + Wt_bytes);

    k_prepM<<<N_, 64, 0, stream>>>(ne, adj, M2);
    k_prepW<<<B_ * T_, 256, 0, stream>>>(te, wp, bp, Wt, bias);
    k_fused<<<dim3(N_ / NB, B_), 256, 0, stream>>>(eb, M2, Wt, bias, out);
}